// Round 7
// baseline (549.968 us; speedup 1.0000x reference)
//
#include <hip/hip_runtime.h>

// ---------------------------------------------------------------------------
// AttentionHead: B=4, C=256, N=4096, QK=64. Column-softmax attention.
// transpose(x->xT bf16) -> proj (QKV from xT) -> colsum (partial col sums of
// 2^S) -> vnorm (V[c][j] *= 1/s_j) -> attn (wave-private, LDS-FREE: P goes
// S-MFMA -> exp2 -> pack -> 8 shfl -> PV A-frag, no barriers in j-loop,
// cc=2 channel split, XCD-pinned) -> mlp (fused 2-layer).
// Workspace: 30,081,024 bytes.
// ---------------------------------------------------------------------------

typedef unsigned short u16;
typedef unsigned int u32;
typedef __attribute__((ext_vector_type(4))) unsigned int u32x4;
typedef __attribute__((ext_vector_type(8))) unsigned short ushort8;
typedef __attribute__((ext_vector_type(8))) __bf16 bf16x8;
typedef __attribute__((ext_vector_type(4))) float f32x4;

#define MFMA16(a, b, c) __builtin_amdgcn_mfma_f32_16x16x32_bf16((a), (b), (c), 0, 0, 0)
#define QSCALE 0.18033688011112042f  // 0.125 * log2(e)

__device__ __forceinline__ u16 f2bf(float f) {  // round-to-nearest-even
  u32 u = __builtin_bit_cast(u32, f);
  u += 0x7FFFu + ((u >> 16) & 1u);
  return (u16)(u >> 16);
}
__device__ __forceinline__ u32 pack2(float lo, float hi) {  // 2 bf16 (trunc)
  u32 a = __builtin_bit_cast(u32, lo), b = __builtin_bit_cast(u32, hi);
  return (a >> 16) | (b & 0xffff0000u);
}
__device__ __forceinline__ bf16x8 ld8(const u16* p) {
  return __builtin_bit_cast(bf16x8, *reinterpret_cast<const ushort8*>(p));
}
__device__ __forceinline__ f32x4 fz4() {
  f32x4 z = {0.f, 0.f, 0.f, 0.f};
  return z;
}

// ---- convert all weight matrices fp32 -> bf16 -----------------------------
__global__ __launch_bounds__(256) void k_convert(
    const float* __restrict__ wq, const float* __restrict__ wk,
    const float* __restrict__ wv, const float* __restrict__ w1,
    const float* __restrict__ w2, u16* __restrict__ dq, u16* __restrict__ dk,
    u16* __restrict__ dv, u16* __restrict__ d1, u16* __restrict__ d2) {
  int i = blockIdx.x * 256 + threadIdx.x;
  if (i < 16384)       dq[i]          = f2bf(wq[i]);
  else if (i < 32768)  dk[i - 16384]  = f2bf(wk[i - 16384]);
  else if (i < 98304)  dv[i - 32768]  = f2bf(wv[i - 32768]);
  else if (i < 163840) d1[i - 98304]  = f2bf(w1[i - 98304]);
  else                 d2[i - 163840] = f2bf(w2[i - 163840]);
}

// ---- x [b][256][4096] fp32 -> xT [b][4096][256] bf16 (LDS-tiled) ----------
__global__ __launch_bounds__(256) void k_transpose(const float* __restrict__ x,
                                                   u16* __restrict__ xT) {
  __shared__ float t[64][65];
  int n0 = blockIdx.x * 64, c0 = blockIdx.y * 64, b = blockIdx.z;
  int tx = threadIdx.x & 63, ty = threadIdx.x >> 6;
  const float* xb = x + ((size_t)b * 256 + c0) * 4096 + n0;
#pragma unroll
  for (int i = 0; i < 64; i += 4) t[ty + i][tx] = xb[(size_t)(ty + i) * 4096 + tx];
  __syncthreads();
  u16* xo = xT + ((size_t)b * 4096 + n0) * 256 + c0;
#pragma unroll
  for (int i = 0; i < 64; i += 4) xo[(size_t)(ty + i) * 256 + tx] = f2bf(t[tx][ty + i]);
}

// ---- fused QKV projection from xT -----------------------------------------
// 16-pos tiles, grid 1024 (b = id&3). Q/K: D[pos][o]; V: D[o][pos].
__global__ __launch_bounds__(256, 4) void k_proj(
    const u16* __restrict__ xT, const u16* __restrict__ wq,
    const float* __restrict__ bQ, const u16* __restrict__ wk,
    const float* __restrict__ bK, const u16* __restrict__ wv,
    const float* __restrict__ bV, const float* __restrict__ PE,
    u16* __restrict__ Qt, u16* __restrict__ Kt, u16* __restrict__ Vc) {
  int b = blockIdx.x & 3, n0 = (blockIdx.x >> 2) * 16;
  int lane = threadIdx.x & 63, wid = threadIdx.x >> 6;
  int l15 = lane & 15, g = lane >> 4;
  const u16* xrow = xT + ((size_t)b * 4096 + n0) * 256;

  f32x4 aq = fz4(), ak = fz4(), av[4];
#pragma unroll
  for (int m = 0; m < 4; ++m) av[m] = fz4();

  for (int kk = 0; kk < 8; ++kk) {
    int c0 = kk * 32 + 8 * g;
    bf16x8 xa = ld8(xrow + l15 * 256 + c0);
    bf16x8 fq = ld8(wq + (16 * wid + l15) * 256 + c0);
    bf16x8 fk = ld8(wk + (16 * wid + l15) * 256 + c0);
    aq = MFMA16(xa, fq, aq);
    ak = MFMA16(xa, fk, ak);
#pragma unroll
    for (int m = 0; m < 4; ++m) {
      bf16x8 fv = ld8(wv + (64 * wid + 16 * m + l15) * 256 + c0);
      av[m] = MFMA16(fv, xa, av[m]);
    }
  }
  int o = 16 * wid + l15;
#pragma unroll
  for (int r = 0; r < 4; ++r) {
    int pos = n0 + 4 * g + r;
    float pe = PE[o * 4096 + pos];
    Qt[((size_t)b * 4096 + pos) * 64 + o] = f2bf((aq[r] + bQ[o] + pe) * QSCALE);
    Kt[((size_t)b * 4096 + pos) * 64 + o] = f2bf(ak[r] + bK[o] + pe);
  }
#pragma unroll
  for (int m = 0; m < 4; ++m)
#pragma unroll
    for (int r = 0; r < 4; ++r) {
      int ov = 64 * wid + 16 * m + 4 * g + r;
      int pos = n0 + l15;
      Vc[((size_t)b * 256 + ov) * 4096 + pos] = f2bf(av[m][r] + bV[ov]);
    }
}

// ---- pass 1: partial column sums of 2^S over 4 i-chunks -------------------
// Grid 1024: combo = id&15 -> (ic,b), jt = id>>4. sp[(ic*4+b)*4096 + j].
__global__ __launch_bounds__(256, 4) void k_colsum(const u16* __restrict__ Qt,
                                                   const u16* __restrict__ Kt,
                                                   float* __restrict__ sp) {
  int combo = blockIdx.x & 15, ic = combo >> 2, b = combo & 3;
  int j0 = (blockIdx.x >> 4) * 64;
  int lane = threadIdx.x & 63, wid = threadIdx.x >> 6;
  int l15 = lane & 15, g = lane >> 4;
  const u16* qb = Qt + (size_t)b * 262144;
  const u16* kb = Kt + (size_t)b * 262144;
  int j = j0 + 16 * wid + l15;
  bf16x8 fk0 = ld8(kb + j * 64 + 8 * g);
  bf16x8 fk1 = ld8(kb + j * 64 + 32 + 8 * g);
  float part = 0.f;
  for (int i0 = ic * 1024; i0 < ic * 1024 + 1024; i0 += 64) {
    f32x4 acc[4];
#pragma unroll
    for (int m = 0; m < 4; ++m) {
      const u16* qr = qb + (i0 + 16 * m + l15) * 64;
      acc[m] = fz4();
      acc[m] = MFMA16(ld8(qr + 8 * g), fk0, acc[m]);
      acc[m] = MFMA16(ld8(qr + 32 + 8 * g), fk1, acc[m]);
    }
#pragma unroll
    for (int m = 0; m < 4; ++m)
#pragma unroll
      for (int r = 0; r < 4; ++r) part += exp2f(acc[m][r]);
  }
  part += __shfl_xor(part, 16);
  part += __shfl_xor(part, 32);
  if (g == 0) sp[((size_t)ic * 4 + b) * 4096 + j] = part;
}

// ---- normalize V in place: V[b][c][j] *= 1/s_j ----------------------------
__global__ __launch_bounds__(256) void k_vnorm(const float* __restrict__ sp,
                                               u16* __restrict__ Vc) {
  int b = blockIdx.x & 3, cb = ((blockIdx.x >> 2) & 7) * 32;
  int jb = (blockIdx.x >> 5) * 512;
  int t = threadIdx.x;
  int j0 = jb + (t & 63) * 8;
  float rs[8];
#pragma unroll
  for (int e = 0; e < 8; ++e) {
    size_t base = (size_t)b * 4096 + j0 + e;
    float s = sp[base] + sp[base + 16384] + sp[base + 32768] + sp[base + 49152];
    rs[e] = 1.0f / s;
  }
  int c0 = cb + (t >> 6);
#pragma unroll
  for (int k = 0; k < 8; ++k) {
    int c = c0 + 4 * k;
    u16* vp = Vc + ((size_t)b * 256 + c) * 4096 + j0;
    ushort8 v = *reinterpret_cast<const ushort8*>(vp);
    ushort8 r;
#pragma unroll
    for (int e = 0; e < 8; ++e)
      r[e] = f2bf(__builtin_bit_cast(float, ((u32)v[e]) << 16) * rs[e]);
    *reinterpret_cast<ushort8*>(vp) = r;
  }
}

// ---- pass 2: attention — LDS-free, barrier-free ---------------------------
// Grid 512: b=id&3, cc=(id>>2)&1, it=id>>3 (id&7 pins (cc,b) per XCD).
// Wave wid owns i-strip ib=i0+16wid, covers all 128 channels of its cc half.
// Per 32-j step: 2x(S-MFMA pair, A=K rows j, B=Q cols i; lane: i=l15,
// j=16jj+4g+r) -> exp2 -> pack -> 8 shfl (g-axis permute at fixed l15)
// -> PV A-frag (row=i=l15, k=j=8g+e) -> 8 independent PV MFMAs.
__global__ __launch_bounds__(256, 2) void k_attn(
    const u16* __restrict__ Qt, const u16* __restrict__ Kt,
    const u16* __restrict__ Vn, u16* __restrict__ attT) {
  int id = blockIdx.x;
  int b = id & 3, cc = (id >> 2) & 1, i0 = (id >> 3) * 64;
  int lane = threadIdx.x & 63, wid = threadIdx.x >> 6;
  int l15 = lane & 15, g = lane >> 4;
  const u16* qb = Qt + (size_t)b * 262144;
  const u16* kb = Kt + (size_t)b * 262144;
  const u16* vb = Vn + ((size_t)b * 256 + cc * 128) * 4096;
  int ib = i0 + 16 * wid;

  int srcA = 32 * (g & 1) + l15;  // shfl sources (constant per lane)
  int srcB = srcA + 16;
  bool hi = (g >= 2);  // this lane's A-frag tile = jj1

  bf16x8 aq[2];  // Q B-frags for the wave's 16 i (col=i=l15, k=8g+e+32h)
#pragma unroll
  for (int h = 0; h < 2; ++h)
    aq[h] = ld8(qb + (ib + l15) * 64 + h * 32 + 8 * g);

  f32x4 oacc[8];  // lane: c = cc*128+16n+l15, i = ib+4g+r
#pragma unroll
  for (int n = 0; n < 8; ++n) oacc[n] = fz4();

#pragma unroll 2
  for (int jg = 0; jg < 4096; jg += 32) {
    // two 16-j S subtiles -> packed exp2 values (lane: i=l15, j=16jj+4g+r)
    u32 v0[2], v1[2];
#pragma unroll
    for (int jj = 0; jj < 2; ++jj) {
      const u16* kr = kb + (size_t)(jg + 16 * jj + l15) * 64 + 8 * g;
      f32x4 s = fz4();
      s = MFMA16(ld8(kr), aq[0], s);
      s = MFMA16(ld8(kr + 32), aq[1], s);
      v0[jj] = pack2(exp2f(s[0]), exp2f(s[1]));
      v1[jj] = pack2(exp2f(s[2]), exp2f(s[3]));
    }
    // PV A-frag via in-wave shuffles (both tiles shuffled, dest selects)
    u32 a00 = __shfl((int)v0[0], srcA), a01 = __shfl((int)v0[1], srcA);
    u32 a10 = __shfl((int)v1[0], srcA), a11 = __shfl((int)v1[1], srcA);
    u32 b00 = __shfl((int)v0[0], srcB), b01 = __shfl((int)v0[1], srcB);
    u32 b10 = __shfl((int)v1[0], srcB), b11 = __shfl((int)v1[1], srcB);
    u32x4 w = {hi ? a01 : a00, hi ? a11 : a10, hi ? b01 : b00, hi ? b11 : b10};
    bf16x8 ap = __builtin_bit_cast(bf16x8, w);
    // 8 independent PV MFMAs over 128 channels
#pragma unroll
    for (int n = 0; n < 8; ++n) {
      bf16x8 bv = ld8(vb + (size_t)(16 * n + l15) * 4096 + jg + 8 * g);
      oacc[n] = MFMA16(ap, bv, oacc[n]);
    }
  }
#pragma unroll
  for (int n = 0; n < 8; ++n) {
    int c = cc * 128 + 16 * n + l15;
#pragma unroll
    for (int r = 0; r < 4; ++r) {
      int pos = ib + 4 * g + r;
      attT[((size_t)b * 4096 + pos) * 256 + c] = f2bf(oacc[n][r]);
    }
  }
}

// ---- fused MLP: mish(W1 att + b1) (LDS) -> W2 .. + b2 + x -----------------
// 32-pos tiles, grid 512 (b = id&3). att read directly from global.
__global__ __launch_bounds__(256, 2) void k_mlp(
    const u16* __restrict__ attT, const u16* __restrict__ w1,
    const float* __restrict__ b1, const u16* __restrict__ w2,
    const float* __restrict__ b2, const float* __restrict__ x,
    float* __restrict__ out) {
  __shared__ u16 hdnS[32][264];
  int b = blockIdx.x & 3, n0 = (blockIdx.x >> 2) * 32;
  int lane = threadIdx.x & 63, wid = threadIdx.x >> 6;
  int l15 = lane & 15, g = lane >> 4;
  const u16* arow = attT + ((size_t)b * 4096 + n0) * 256;

  f32x4 h4[2][4];
#pragma unroll
  for (int m = 0; m < 2; ++m)
#pragma unroll
    for (int n = 0; n < 4; ++n) h4[m][n] = fz4();
  for (int kk = 0; kk < 8; ++kk) {
    int c0 = kk * 32 + 8 * g;
    bf16x8 am[2];
#pragma unroll
    for (int m = 0; m < 2; ++m) am[m] = ld8(arow + (16 * m + l15) * 256 + c0);
#pragma unroll
    for (int n = 0; n < 4; ++n) {
      bf16x8 bn = ld8(w1 + (64 * wid + 16 * n + l15) * 256 + c0);
#pragma unroll
      for (int m = 0; m < 2; ++m) h4[m][n] = MFMA16(am[m], bn, h4[m][n]);
    }
  }
#pragma unroll
  for (int m = 0; m < 2; ++m)
#pragma unroll
    for (int n = 0; n < 4; ++n) {
      int hh = 64 * wid + 16 * n + l15;
      float bb = b1[hh];
#pragma unroll
      for (int r = 0; r < 4; ++r) {
        float v = h4[m][n][r] + bb;
        float sp_ = (v > 15.f) ? v : __logf(1.f + __expf(v));
        float e2 = __expf(-2.f * sp_);
        float th = (1.f - e2) / (1.f + e2);
        hdnS[16 * m + 4 * g + r][hh] = f2bf(v * th);
      }
    }
  __syncthreads();

  f32x4 acc[4][2];
#pragma unroll
  for (int m = 0; m < 4; ++m)
#pragma unroll
    for (int n = 0; n < 2; ++n) acc[m][n] = fz4();
  for (int kk = 0; kk < 8; ++kk) {
    int c0 = kk * 32 + 8 * g;
    bf16x8 bn[2];
#pragma unroll
    for (int n = 0; n < 2; ++n) bn[n] = ld8(&hdnS[16 * n + l15][c0]);
#pragma unroll
    for (int m = 0; m < 4; ++m) {
      bf16x8 am = ld8(w2 + (64 * wid + 16 * m + l15) * 256 + c0);
#pragma unroll
      for (int n = 0; n < 2; ++n) acc[m][n] = MFMA16(am, bn[n], acc[m][n]);
    }
  }
#pragma unroll
  for (int m = 0; m < 4; ++m)
#pragma unroll
    for (int n = 0; n < 2; ++n)
#pragma unroll
      for (int r = 0; r < 4; ++r) {
        int o = 64 * wid + 16 * m + 4 * g + r;
        int pos = n0 + 16 * n + l15;
        size_t idx = ((size_t)b * 256 + o) * 4096 + pos;
        out[idx] = acc[m][n][r] + b2[o] + x[idx];
      }
}

// ---- workspace layout (bytes) ---------------------------------------------
#define WS_XT 0u          //  8,388,608  xT  [4][4096][256] bf16
#define WS_QT 8388608u    //  2,097,152  Qt  [4][4096][64]  bf16 (pre-scaled)
#define WS_KT 10485760u   //  2,097,152  Kt  [4][4096][64]  bf16
#define WS_VC 12582912u   //  8,388,608  Vc  [4][256][4096] bf16 (normed in place)
#define WS_SP 20971520u   //    262,144  sp  [4 ic][4 b][4096] fp32
#define WS_ATT 21233664u  //  8,388,608  attT[4][4096][256] bf16
#define WS_WQ 29622272u   //     32,768
#define WS_WK 29655040u   //     32,768
#define WS_WV 29687808u   //    131,072
#define WS_W1 29818880u   //    131,072
#define WS_W2 29949952u   //    131,072   (end: 30,081,024)

extern "C" void kernel_launch(void* const* d_in, const int* in_sizes, int n_in,
                              void* d_out, int out_size, void* d_ws, size_t ws_size,
                              hipStream_t stream) {
  (void)in_sizes; (void)n_in; (void)out_size; (void)ws_size;
  const float* x  = (const float*)d_in[0];
  const float* WQ = (const float*)d_in[1];
  const float* bQ = (const float*)d_in[2];
  const float* WK = (const float*)d_in[3];
  const float* bK = (const float*)d_in[4];
  const float* WV = (const float*)d_in[5];
  const float* bV = (const float*)d_in[6];
  const float* PE = (const float*)d_in[7];
  const float* W1 = (const float*)d_in[8];
  const float* b1 = (const float*)d_in[9];
  const float* W2 = (const float*)d_in[10];
  const float* b2 = (const float*)d_in[11];
  float* out = (float*)d_out;
  char* ws = (char*)d_ws;

  u16* xT   = (u16*)(ws + WS_XT);
  u16* Qt   = (u16*)(ws + WS_QT);
  u16* Kt   = (u16*)(ws + WS_KT);
  u16* Vc   = (u16*)(ws + WS_VC);
  float* sp = (float*)(ws + WS_SP);
  u16* attT = (u16*)(ws + WS_ATT);
  u16* wqB  = (u16*)(ws + WS_WQ);
  u16* wkB  = (u16*)(ws + WS_WK);
  u16* wvB  = (u16*)(ws + WS_WV);
  u16* w1B  = (u16*)(ws + WS_W1);
  u16* w2B  = (u16*)(ws + WS_W2);

  k_convert<<<896, 256, 0, stream>>>(WQ, WK, WV, W1, W2, wqB, wkB, wvB, w1B, w2B);
  k_transpose<<<dim3(64, 4, 4), 256, 0, stream>>>(x, xT);
  k_proj<<<1024, 256, 0, stream>>>(xT, wqB, bQ, wkB, bK, wvB, bV, PE, Qt, Kt, Vc);
  k_colsum<<<1024, 256, 0, stream>>>(Qt, Kt, sp);
  k_vnorm<<<256, 256, 0, stream>>>(sp, Vc);
  k_attn<<<512, 256, 0, stream>>>(Qt, Kt, Vc, attT);
  k_mlp<<<512, 256, 0, stream>>>(attT, w1B, b1, w2B, b2, x, out);
}

// Round 8
// 335.296 us; speedup vs baseline: 1.6402x; 1.6402x over previous
//
#include <hip/hip_runtime.h>

// ---------------------------------------------------------------------------
// AttentionHead: B=4, C=256, N=4096, QK=64. Column-softmax attention.
// convert -> transpose(x->xT bf16) -> proj (QKV) -> colsum (partial col sums
// of 2^S) -> vnorm (V[c][j] *= 1/s_j) -> attn (R1 shape: 64i x 256c blocks,
// block-wide P in LDS, 2 barriers/step, b64 P-writes, exp2, 3 blocks/CU,
// XCD-pinned) -> mlp (fused 2-layer).
// Workspace: 30,081,024 bytes.
// ---------------------------------------------------------------------------

typedef unsigned short u16;
typedef unsigned int u32;
typedef __attribute__((ext_vector_type(2))) unsigned int u32x2;
typedef __attribute__((ext_vector_type(8))) unsigned short ushort8;
typedef __attribute__((ext_vector_type(8))) __bf16 bf16x8;
typedef __attribute__((ext_vector_type(4))) float f32x4;

#define MFMA16(a, b, c) __builtin_amdgcn_mfma_f32_16x16x32_bf16((a), (b), (c), 0, 0, 0)
#define QSCALE 0.18033688011112042f  // 0.125 * log2(e)

__device__ __forceinline__ u16 f2bf(float f) {  // round-to-nearest-even
  u32 u = __builtin_bit_cast(u32, f);
  u += 0x7FFFu + ((u >> 16) & 1u);
  return (u16)(u >> 16);
}
__device__ __forceinline__ u32 pack2(float lo, float hi) {  // 2 bf16 (trunc)
  u32 a = __builtin_bit_cast(u32, lo), b = __builtin_bit_cast(u32, hi);
  return (a >> 16) | (b & 0xffff0000u);
}
__device__ __forceinline__ bf16x8 ld8(const u16* p) {
  return __builtin_bit_cast(bf16x8, *reinterpret_cast<const ushort8*>(p));
}
__device__ __forceinline__ f32x4 fz4() {
  f32x4 z = {0.f, 0.f, 0.f, 0.f};
  return z;
}

// ---- convert all weight matrices fp32 -> bf16 -----------------------------
__global__ __launch_bounds__(256) void k_convert(
    const float* __restrict__ wq, const float* __restrict__ wk,
    const float* __restrict__ wv, const float* __restrict__ w1,
    const float* __restrict__ w2, u16* __restrict__ dq, u16* __restrict__ dk,
    u16* __restrict__ dv, u16* __restrict__ d1, u16* __restrict__ d2) {
  int i = blockIdx.x * 256 + threadIdx.x;
  if (i < 16384)       dq[i]          = f2bf(wq[i]);
  else if (i < 32768)  dk[i - 16384]  = f2bf(wk[i - 16384]);
  else if (i < 98304)  dv[i - 32768]  = f2bf(wv[i - 32768]);
  else if (i < 163840) d1[i - 98304]  = f2bf(w1[i - 98304]);
  else                 d2[i - 163840] = f2bf(w2[i - 163840]);
}

// ---- x [b][256][4096] fp32 -> xT [b][4096][256] bf16 (LDS-tiled) ----------
__global__ __launch_bounds__(256) void k_transpose(const float* __restrict__ x,
                                                   u16* __restrict__ xT) {
  __shared__ float t[64][65];
  int n0 = blockIdx.x * 64, c0 = blockIdx.y * 64, b = blockIdx.z;
  int tx = threadIdx.x & 63, ty = threadIdx.x >> 6;
  const float* xb = x + ((size_t)b * 256 + c0) * 4096 + n0;
#pragma unroll
  for (int i = 0; i < 64; i += 4) t[ty + i][tx] = xb[(size_t)(ty + i) * 4096 + tx];
  __syncthreads();
  u16* xo = xT + ((size_t)b * 4096 + n0) * 256 + c0;
#pragma unroll
  for (int i = 0; i < 64; i += 4) xo[(size_t)(ty + i) * 256 + tx] = f2bf(t[tx][ty + i]);
}

// ---- fused QKV projection from xT -----------------------------------------
// 16-pos tiles, grid 1024 (b = id&3). Q/K: D[pos][o]; V: D[o][pos].
__global__ __launch_bounds__(256, 4) void k_proj(
    const u16* __restrict__ xT, const u16* __restrict__ wq,
    const float* __restrict__ bQ, const u16* __restrict__ wk,
    const float* __restrict__ bK, const u16* __restrict__ wv,
    const float* __restrict__ bV, const float* __restrict__ PE,
    u16* __restrict__ Qt, u16* __restrict__ Kt, u16* __restrict__ Vc) {
  int b = blockIdx.x & 3, n0 = (blockIdx.x >> 2) * 16;
  int lane = threadIdx.x & 63, wid = threadIdx.x >> 6;
  int l15 = lane & 15, g = lane >> 4;
  const u16* xrow = xT + ((size_t)b * 4096 + n0) * 256;

  f32x4 aq = fz4(), ak = fz4(), av[4];
#pragma unroll
  for (int m = 0; m < 4; ++m) av[m] = fz4();

  for (int kk = 0; kk < 8; ++kk) {
    int c0 = kk * 32 + 8 * g;
    bf16x8 xa = ld8(xrow + l15 * 256 + c0);
    bf16x8 fq = ld8(wq + (16 * wid + l15) * 256 + c0);
    bf16x8 fk = ld8(wk + (16 * wid + l15) * 256 + c0);
    aq = MFMA16(xa, fq, aq);
    ak = MFMA16(xa, fk, ak);
#pragma unroll
    for (int m = 0; m < 4; ++m) {
      bf16x8 fv = ld8(wv + (64 * wid + 16 * m + l15) * 256 + c0);
      av[m] = MFMA16(fv, xa, av[m]);
    }
  }
  int o = 16 * wid + l15;
#pragma unroll
  for (int r = 0; r < 4; ++r) {
    int pos = n0 + 4 * g + r;
    float pe = PE[o * 4096 + pos];
    Qt[((size_t)b * 4096 + pos) * 64 + o] = f2bf((aq[r] + bQ[o] + pe) * QSCALE);
    Kt[((size_t)b * 4096 + pos) * 64 + o] = f2bf(ak[r] + bK[o] + pe);
  }
#pragma unroll
  for (int m = 0; m < 4; ++m)
#pragma unroll
    for (int r = 0; r < 4; ++r) {
      int ov = 64 * wid + 16 * m + 4 * g + r;
      int pos = n0 + l15;
      Vc[((size_t)b * 256 + ov) * 4096 + pos] = f2bf(av[m][r] + bV[ov]);
    }
}

// ---- pass 1: partial column sums of 2^S over 4 i-chunks -------------------
// Grid 1024: combo = id&15 -> (ic,b), jt = id>>4. sp[(ic*4+b)*4096 + j].
__global__ __launch_bounds__(256, 4) void k_colsum(const u16* __restrict__ Qt,
                                                   const u16* __restrict__ Kt,
                                                   float* __restrict__ sp) {
  int combo = blockIdx.x & 15, ic = combo >> 2, b = combo & 3;
  int j0 = (blockIdx.x >> 4) * 64;
  int lane = threadIdx.x & 63, wid = threadIdx.x >> 6;
  int l15 = lane & 15, g = lane >> 4;
  const u16* qb = Qt + (size_t)b * 262144;
  const u16* kb = Kt + (size_t)b * 262144;
  int j = j0 + 16 * wid + l15;
  bf16x8 fk0 = ld8(kb + j * 64 + 8 * g);
  bf16x8 fk1 = ld8(kb + j * 64 + 32 + 8 * g);
  float part = 0.f;
  for (int i0 = ic * 1024; i0 < ic * 1024 + 1024; i0 += 64) {
    f32x4 acc[4];
#pragma unroll
    for (int m = 0; m < 4; ++m) {
      const u16* qr = qb + (i0 + 16 * m + l15) * 64;
      acc[m] = fz4();
      acc[m] = MFMA16(ld8(qr + 8 * g), fk0, acc[m]);
      acc[m] = MFMA16(ld8(qr + 32 + 8 * g), fk1, acc[m]);
    }
#pragma unroll
    for (int m = 0; m < 4; ++m)
#pragma unroll
      for (int r = 0; r < 4; ++r) part += exp2f(acc[m][r]);
  }
  part += __shfl_xor(part, 16);
  part += __shfl_xor(part, 32);
  if (g == 0) sp[((size_t)ic * 4 + b) * 4096 + j] = part;
}

// ---- normalize V in place: V[b][c][j] *= 1/s_j ----------------------------
__global__ __launch_bounds__(256) void k_vnorm(const float* __restrict__ sp,
                                               u16* __restrict__ Vc) {
  int b = blockIdx.x & 3, cb = ((blockIdx.x >> 2) & 7) * 32;
  int jb = (blockIdx.x >> 5) * 512;
  int t = threadIdx.x;
  int j0 = jb + (t & 63) * 8;
  float rs[8];
#pragma unroll
  for (int e = 0; e < 8; ++e) {
    size_t base = (size_t)b * 4096 + j0 + e;
    float s = sp[base] + sp[base + 16384] + sp[base + 32768] + sp[base + 49152];
    rs[e] = 1.0f / s;
  }
  int c0 = cb + (t >> 6);
#pragma unroll
  for (int k = 0; k < 8; ++k) {
    int c = c0 + 4 * k;
    u16* vp = Vc + ((size_t)b * 256 + c) * 4096 + j0;
    ushort8 v = *reinterpret_cast<const ushort8*>(vp);
    ushort8 r;
#pragma unroll
    for (int e = 0; e < 8; ++e)
      r[e] = f2bf(__builtin_bit_cast(float, ((u32)v[e]) << 16) * rs[e]);
    *reinterpret_cast<ushort8*>(vp) = r;
  }
}

// ---- pass 2: attention (R1 shape + b64 P-writes + exp2) -------------------
// Grid 256: b = id&3 (XCD pin: each XCD sees one b, ~3 MB L2 set),
// i0 = (id>>2)*64. Block covers 64 i x ALL 256 channels (40 MFMA / 64-j step).
// S: A=K rows j, B=Q cols i -> lane holds S[i=i0+16m+l15][j=jg+16wid+4g+r],
// 4 consecutive j -> one ds_write_b64 per m into P[i-local][j-local] (pitch 72).
// PV: A = P rows i (ds_read_b128), B = V rows c; oacc[m][n] over 4x4 subtiles.
__global__ __launch_bounds__(256, 3) void k_attn(
    const u16* __restrict__ Qt, const u16* __restrict__ Kt,
    const u16* __restrict__ Vn, u16* __restrict__ attT) {
  __shared__ u16 P[64][72];
  int id = blockIdx.x;
  int b = id & 3, i0 = (id >> 2) * 64;
  int lane = threadIdx.x & 63, wid = threadIdx.x >> 6;
  int l15 = lane & 15, g = lane >> 4;
  const u16* qb = Qt + (size_t)b * 262144;
  const u16* kb = Kt + (size_t)b * 262144;
  const u16* vb = Vn + (size_t)b * 1048576;

  bf16x8 aq[4][2];  // Q B-frags: subtile m covers i = i0+16m+l15 (col), k-half h
#pragma unroll
  for (int m = 0; m < 4; ++m)
#pragma unroll
    for (int h = 0; h < 2; ++h)
      aq[m][h] = ld8(qb + (i0 + 16 * m + l15) * 64 + h * 32 + 8 * g);

  f32x4 oacc[4][4];  // lane: i = i0+16m+4g+r, c = 64wid+16n+l15
#pragma unroll
  for (int m = 0; m < 4; ++m)
#pragma unroll
    for (int n = 0; n < 4; ++n) oacc[m][n] = fz4();

  for (int jg = 0; jg < 4096; jg += 64) {
    // K A-frags for this wave's j-subtile (rows j = jg+16wid+l15)
    const u16* kr = kb + (size_t)(jg + 16 * wid + l15) * 64 + 8 * g;
    bf16x8 fk0 = ld8(kr);
    bf16x8 fk1 = ld8(kr + 32);
    // S -> exp2 -> P (lane: i = 16m+l15, j = 16wid+4g+0..3 -> b64 write)
#pragma unroll
    for (int m = 0; m < 4; ++m) {
      f32x4 s = fz4();
      s = MFMA16(fk0, aq[m][0], s);
      s = MFMA16(fk1, aq[m][1], s);
      u32x2 pw = {pack2(exp2f(s[0]), exp2f(s[1])),
                  pack2(exp2f(s[2]), exp2f(s[3]))};
      *reinterpret_cast<u32x2*>(&P[16 * m + l15][16 * wid + 4 * g]) = pw;
    }
    __syncthreads();
    // PV: 4 m x 4 n x 2 h = 32 MFMAs
#pragma unroll
    for (int h = 0; h < 2; ++h) {
      bf16x8 ap[4];
#pragma unroll
      for (int m = 0; m < 4; ++m) ap[m] = ld8(&P[16 * m + l15][h * 32 + 8 * g]);
#pragma unroll
      for (int n = 0; n < 4; ++n) {
        bf16x8 fv = ld8(vb + (size_t)(64 * wid + 16 * n + l15) * 4096 + jg + h * 32 + 8 * g);
#pragma unroll
        for (int m = 0; m < 4; ++m) oacc[m][n] = MFMA16(ap[m], fv, oacc[m][n]);
      }
    }
    __syncthreads();
  }
#pragma unroll
  for (int m = 0; m < 4; ++m)
#pragma unroll
    for (int n = 0; n < 4; ++n) {
      int c = 64 * wid + 16 * n + l15;
#pragma unroll
      for (int r = 0; r < 4; ++r) {
        int pos = i0 + 16 * m + 4 * g + r;
        attT[((size_t)b * 4096 + pos) * 256 + c] = f2bf(oacc[m][n][r]);
      }
    }
}

// ---- fused MLP: mish(W1 att + b1) (LDS) -> W2 .. + b2 + x -----------------
// 32-pos tiles, grid 512 (b = id&3). att read directly from global.
__global__ __launch_bounds__(256, 2) void k_mlp(
    const u16* __restrict__ attT, const u16* __restrict__ w1,
    const float* __restrict__ b1, const u16* __restrict__ w2,
    const float* __restrict__ b2, const float* __restrict__ x,
    float* __restrict__ out) {
  __shared__ u16 hdnS[32][264];
  int b = blockIdx.x & 3, n0 = (blockIdx.x >> 2) * 32;
  int lane = threadIdx.x & 63, wid = threadIdx.x >> 6;
  int l15 = lane & 15, g = lane >> 4;
  const u16* arow = attT + ((size_t)b * 4096 + n0) * 256;

  f32x4 h4[2][4];
#pragma unroll
  for (int m = 0; m < 2; ++m)
#pragma unroll
    for (int n = 0; n < 4; ++n) h4[m][n] = fz4();
  for (int kk = 0; kk < 8; ++kk) {
    int c0 = kk * 32 + 8 * g;
    bf16x8 am[2];
#pragma unroll
    for (int m = 0; m < 2; ++m) am[m] = ld8(arow + (16 * m + l15) * 256 + c0);
#pragma unroll
    for (int n = 0; n < 4; ++n) {
      bf16x8 bn = ld8(w1 + (64 * wid + 16 * n + l15) * 256 + c0);
#pragma unroll
      for (int m = 0; m < 2; ++m) h4[m][n] = MFMA16(am[m], bn, h4[m][n]);
    }
  }
#pragma unroll
  for (int m = 0; m < 2; ++m)
#pragma unroll
    for (int n = 0; n < 4; ++n) {
      int hh = 64 * wid + 16 * n + l15;
      float bb = b1[hh];
#pragma unroll
      for (int r = 0; r < 4; ++r) {
        float v = h4[m][n][r] + bb;
        float sp_ = (v > 15.f) ? v : __logf(1.f + __expf(v));
        float e2 = __expf(-2.f * sp_);
        float th = (1.f - e2) / (1.f + e2);
        hdnS[16 * m + 4 * g + r][hh] = f2bf(v * th);
      }
    }
  __syncthreads();

  f32x4 acc[4][2];
#pragma unroll
  for (int m = 0; m < 4; ++m)
#pragma unroll
    for (int n = 0; n < 2; ++n) acc[m][n] = fz4();
  for (int kk = 0; kk < 8; ++kk) {
    int c0 = kk * 32 + 8 * g;
    bf16x8 bn[2];
#pragma unroll
    for (int n = 0; n < 2; ++n) bn[n] = ld8(&hdnS[16 * n + l15][c0]);
#pragma unroll
    for (int m = 0; m < 4; ++m) {
      bf16x8 am = ld8(w2 + (64 * wid + 16 * m + l15) * 256 + c0);
#pragma unroll
      for (int n = 0; n < 2; ++n) acc[m][n] = MFMA16(am, bn[n], acc[m][n]);
    }
  }
#pragma unroll
  for (int m = 0; m < 4; ++m)
#pragma unroll
    for (int n = 0; n < 2; ++n)
#pragma unroll
      for (int r = 0; r < 4; ++r) {
        int o = 64 * wid + 16 * m + 4 * g + r;
        int pos = n0 + 16 * n + l15;
        size_t idx = ((size_t)b * 256 + o) * 4096 + pos;
        out[idx] = acc[m][n][r] + b2[o] + x[idx];
      }
}

// ---- workspace layout (bytes) ---------------------------------------------
#define WS_XT 0u          //  8,388,608  xT  [4][4096][256] bf16
#define WS_QT 8388608u    //  2,097,152  Qt  [4][4096][64]  bf16 (pre-scaled)
#define WS_KT 10485760u   //  2,097,152  Kt  [4][4096][64]  bf16
#define WS_VC 12582912u   //  8,388,608  Vc  [4][256][4096] bf16 (normed in place)
#define WS_SP 20971520u   //    262,144  sp  [4 ic][4 b][4096] fp32
#define WS_ATT 21233664u  //  8,388,608  attT[4][4096][256] bf16
#define WS_WQ 29622272u   //     32,768
#define WS_WK 29655040u   //     32,768
#define WS_WV 29687808u   //    131,072
#define WS_W1 29818880u   //    131,072
#define WS_W2 29949952u   //    131,072   (end: 30,081,024)

extern "C" void kernel_launch(void* const* d_in, const int* in_sizes, int n_in,
                              void* d_out, int out_size, void* d_ws, size_t ws_size,
                              hipStream_t stream) {
  (void)in_sizes; (void)n_in; (void)out_size; (void)ws_size;
  const float* x  = (const float*)d_in[0];
  const float* WQ = (const float*)d_in[1];
  const float* bQ = (const float*)d_in[2];
  const float* WK = (const float*)d_in[3];
  const float* bK = (const float*)d_in[4];
  const float* WV = (const float*)d_in[5];
  const float* bV = (const float*)d_in[6];
  const float* PE = (const float*)d_in[7];
  const float* W1 = (const float*)d_in[8];
  const float* b1 = (const float*)d_in[9];
  const float* W2 = (const float*)d_in[10];
  const float* b2 = (const float*)d_in[11];
  float* out = (float*)d_out;
  char* ws = (char*)d_ws;

  u16* xT   = (u16*)(ws + WS_XT);
  u16* Qt   = (u16*)(ws + WS_QT);
  u16* Kt   = (u16*)(ws + WS_KT);
  u16* Vc   = (u16*)(ws + WS_VC);
  float* sp = (float*)(ws + WS_SP);
  u16* attT = (u16*)(ws + WS_ATT);
  u16* wqB  = (u16*)(ws + WS_WQ);
  u16* wkB  = (u16*)(ws + WS_WK);
  u16* wvB  = (u16*)(ws + WS_WV);
  u16* w1B  = (u16*)(ws + WS_W1);
  u16* w2B  = (u16*)(ws + WS_W2);

  k_convert<<<896, 256, 0, stream>>>(WQ, WK, WV, W1, W2, wqB, wkB, wvB, w1B, w2B);
  k_transpose<<<dim3(64, 4, 4), 256, 0, stream>>>(x, xT);
  k_proj<<<1024, 256, 0, stream>>>(xT, wqB, bQ, wkB, bK, wvB, bV, PE, Qt, Kt, Vc);
  k_colsum<<<1024, 256, 0, stream>>>(Qt, Kt, sp);
  k_vnorm<<<256, 256, 0, stream>>>(sp, Vc);
  k_attn<<<256, 256, 0, stream>>>(Qt, Kt, Vc, attT);
  k_mlp<<<512, 256, 0, stream>>>(attT, w1B, b1, w2B, b2, x, out);
}